// Round 2
// baseline (636.582 us; speedup 1.0000x reference)
//
#include <hip/hip_runtime.h>
#include <stdint.h>

#define N_NODES 10000
#define N_EDGES 160000
#define D 512
#define TOT (N_NODES * D)          // 5,120,000

// ---------------- threefry2x32 (exact JAX semantics) ----------------
__host__ __device__ inline uint32_t rotl32(uint32_t v, int r) {
    return (v << r) | (v >> (32 - r));
}

__host__ __device__ inline void tf2x32(uint32_t k0, uint32_t k1,
                                       uint32_t& x0, uint32_t& x1) {
    uint32_t k2 = k0 ^ k1 ^ 0x1BD11BDAu;
    x0 += k0; x1 += k1;
    // round block 1 (rot 13,15,26,6)
    x0 += x1; x1 = rotl32(x1, 13); x1 ^= x0;
    x0 += x1; x1 = rotl32(x1, 15); x1 ^= x0;
    x0 += x1; x1 = rotl32(x1, 26); x1 ^= x0;
    x0 += x1; x1 = rotl32(x1,  6); x1 ^= x0;
    x0 += k1; x1 += k2 + 1u;
    // round block 2 (rot 17,29,16,24)
    x0 += x1; x1 = rotl32(x1, 17); x1 ^= x0;
    x0 += x1; x1 = rotl32(x1, 29); x1 ^= x0;
    x0 += x1; x1 = rotl32(x1, 16); x1 ^= x0;
    x0 += x1; x1 = rotl32(x1, 24); x1 ^= x0;
    x0 += k2; x1 += k0 + 2u;
    // round block 3 (rot 13,15,26,6)
    x0 += x1; x1 = rotl32(x1, 13); x1 ^= x0;
    x0 += x1; x1 = rotl32(x1, 15); x1 ^= x0;
    x0 += x1; x1 = rotl32(x1, 26); x1 ^= x0;
    x0 += x1; x1 = rotl32(x1,  6); x1 ^= x0;
    x0 += k0; x1 += k1 + 3u;
    // round block 4 (rot 17,29,16,24)
    x0 += x1; x1 = rotl32(x1, 17); x1 ^= x0;
    x0 += x1; x1 = rotl32(x1, 29); x1 ^= x0;
    x0 += x1; x1 = rotl32(x1, 16); x1 ^= x0;
    x0 += x1; x1 = rotl32(x1, 24); x1 ^= x0;
    x0 += k1; x1 += k2 + 4u;
    // round block 5 (rot 13,15,26,6)
    x0 += x1; x1 = rotl32(x1, 13); x1 ^= x0;
    x0 += x1; x1 = rotl32(x1, 15); x1 ^= x0;
    x0 += x1; x1 = rotl32(x1, 26); x1 ^= x0;
    x0 += x1; x1 = rotl32(x1,  6); x1 ^= x0;
    x0 += k2; x1 += k0 + 5u;
}

// ---------------- degree histogram ----------------
__global__ void hist_kernel(const int* __restrict__ src, const int* __restrict__ dst,
                            int* __restrict__ deg_out, int* __restrict__ deg_in) {
    int e = blockIdx.x * 256 + threadIdx.x;
    if (e >= N_EDGES) return;
    atomicAdd(&deg_out[src[e]], 1);
    atomicAdd(&deg_in[dst[e]], 1);
}

// ---------------- exclusive scan over deg_in + norm factors ----------------
__global__ void scan_kernel(const int* __restrict__ deg_in, const int* __restrict__ deg_out,
                            int* __restrict__ row_ptr,
                            float* __restrict__ rn_in, float* __restrict__ rn_out) {
    __shared__ int smem[256];
    __shared__ int base_s;
    int tid = threadIdx.x;
    if (tid == 0) base_s = 0;
    __syncthreads();
    for (int start = 0; start < N_NODES; start += 256) {
        int i = start + tid;
        int v = (i < N_NODES) ? deg_in[i] : 0;
        smem[tid] = v;
        __syncthreads();
        for (int off = 1; off < 256; off <<= 1) {
            int t = (tid >= off) ? smem[tid - off] : 0;
            __syncthreads();
            smem[tid] += t;
            __syncthreads();
        }
        int incl = smem[tid];
        int excl = incl - v;
        if (i < N_NODES) {
            row_ptr[i] = base_s + excl;
            rn_in[i]  = 1.0f / sqrtf(fmaxf((float)v, 1.0f));
            int o = deg_out[i];
            rn_out[i] = 1.0f / sqrtf(fmaxf((float)o, 1.0f));
        }
        __syncthreads();
        if (tid == 255) base_s += smem[255];
        __syncthreads();
    }
    if (tid == 0) row_ptr[N_NODES] = base_s;
}

// ---------------- CSR fill (edges grouped by dst) ----------------
__global__ void fill_kernel(const int* __restrict__ src, const int* __restrict__ dst,
                            const float* __restrict__ ew, const int* __restrict__ row_ptr,
                            int* __restrict__ cursor,
                            int* __restrict__ csr_src, float* __restrict__ csr_w) {
    int e = blockIdx.x * 256 + threadIdx.x;
    if (e >= N_EDGES) return;
    int v = dst[e];
    int pos = atomicAdd(&cursor[v], 1);
    int idx = row_ptr[v] + pos;
    csr_src[idx] = src[e];
    csr_w[idx] = ew[e];
}

// ---------------- dropout (partitionable threefry) + src-norm scale ----------
// JAX >= 0.4.30 default (jax_threefry_partitionable=True):
//   bits[j] = let (a,b) = cipher(k0,k1, x0=hi32(j)=0, x1=lo32(j)=j) in a ^ b
//   u = bitcast((bits>>9)|0x3f800000, f32) - 1;  keep = u < 0.8f
__global__ __launch_bounds__(256)
void dropout_kernel(const float* __restrict__ x, float* __restrict__ y,
                    const float* __restrict__ rn_out, uint32_t k0, uint32_t k1) {
    int t = blockIdx.x * 256 + threadIdx.x;   // one float4 per thread
    int j = t * 4;
    if (j >= TOT) return;
    float4 xv = *(const float4*)&x[j];
    float w = rn_out[j >> 9];                 // row = j/512 (4 | 512, same row)
    float r[4];
    uint32_t jj = (uint32_t)j;
#pragma unroll
    for (int i = 0; i < 4; ++i) {
        uint32_t c0 = 0u, c1 = jj + (uint32_t)i;
        tf2x32(k0, k1, c0, c1);
        uint32_t bits = c0 ^ c1;
        float u = __uint_as_float((bits >> 9) | 0x3f800000u) - 1.0f;
        float xi = (&xv.x)[i];
        r[i] = (u < 0.8f) ? (xi / 0.8f) * w : 0.0f;
    }
    *(float4*)&y[j] = make_float4(r[0], r[1], r[2], r[3]);
}

// ---------------- edge aggregation: agg[v,:] = sum_e w_e * y[src_e,:] ----------------
__global__ __launch_bounds__(128)
void aggregate_kernel(const float* __restrict__ y, const int* __restrict__ row_ptr,
                      const int* __restrict__ csr_src, const float* __restrict__ csr_w,
                      float* __restrict__ agg) {
    int v = blockIdx.x;
    int tid = threadIdx.x;            // 128 threads * float4 = 512 cols
    int beg = row_ptr[v], end = row_ptr[v + 1];
    const float4* y4 = (const float4*)y;
    float4 acc = make_float4(0.f, 0.f, 0.f, 0.f);
    for (int k = beg; k < end; ++k) {
        int s = csr_src[k];
        float w = csr_w[k];
        float4 xv = y4[s * 128 + tid];
        acc.x += w * xv.x;
        acc.y += w * xv.y;
        acc.z += w * xv.z;
        acc.w += w * xv.w;
    }
    ((float4*)agg)[v * 128 + tid] = acc;
}

// ---------------- fp32 GEMM: C = A[M,512] @ W[512,512], epilogue norm+bias(+ELU) ----
#define BM 128
#define BN 64
#define BK 16
__global__ __launch_bounds__(256)
void gemm_kernel(const float* __restrict__ A, const float* __restrict__ W,
                 const float* __restrict__ bias, const float* __restrict__ rn_in,
                 float* __restrict__ C, int act) {
    __shared__ float As[BK][BM];   // 8 KB
    __shared__ float Bs[BK][BN];   // 4 KB
    int tid = threadIdx.x;
    int tx = tid & 15;             // 16 col-groups of 4
    int ty = tid >> 4;             // 16 row-groups of 8
    int row0 = blockIdx.y * BM;
    int col0 = blockIdx.x * BN;

    float acc[8][4];
#pragma unroll
    for (int i = 0; i < 8; ++i)
#pragma unroll
        for (int j = 0; j < 4; ++j) acc[i][j] = 0.f;

    for (int k0 = 0; k0 < 512; k0 += BK) {
        // stage A: 128 rows x 16 k  (2 float4 per thread)
#pragma unroll
        for (int r = 0; r < 2; ++r) {
            int q = tid + r * 256;            // [0,512)
            int ar = q >> 2;                  // row in tile
            int kseg = (q & 3) * 4;           // k offset
            int grow = row0 + ar;
            float4 av = (grow < N_NODES)
                ? *(const float4*)&A[(size_t)grow * 512 + k0 + kseg]
                : make_float4(0.f, 0.f, 0.f, 0.f);
            As[kseg + 0][ar] = av.x;
            As[kseg + 1][ar] = av.y;
            As[kseg + 2][ar] = av.z;
            As[kseg + 3][ar] = av.w;
        }
        // stage B: 16 k x 64 cols (1 float4 per thread)
        {
            int krow = tid >> 4;
            int cseg = (tid & 15) * 4;
            *(float4*)&Bs[krow][cseg] =
                *(const float4*)&W[(size_t)(k0 + krow) * 512 + col0 + cseg];
        }
        __syncthreads();
#pragma unroll
        for (int kk = 0; kk < BK; ++kk) {
            float a[8], b[4];
            *(float4*)&a[0] = *(const float4*)&As[kk][ty * 8];
            *(float4*)&a[4] = *(const float4*)&As[kk][ty * 8 + 4];
            *(float4*)&b[0] = *(const float4*)&Bs[kk][tx * 4];
#pragma unroll
            for (int i = 0; i < 8; ++i)
#pragma unroll
                for (int j = 0; j < 4; ++j) acc[i][j] += a[i] * b[j];
        }
        __syncthreads();
    }

    float4 b4 = *(const float4*)&bias[col0 + tx * 4];
#pragma unroll
    for (int i = 0; i < 8; ++i) {
        int gr = row0 + ty * 8 + i;
        if (gr >= N_NODES) continue;
        float rn = rn_in[gr];
        float4 vv;
        vv.x = acc[i][0] * rn + b4.x;
        vv.y = acc[i][1] * rn + b4.y;
        vv.z = acc[i][2] * rn + b4.z;
        vv.w = acc[i][3] * rn + b4.w;
        if (act) {
            vv.x = (vv.x > 0.f) ? vv.x : expm1f(vv.x);
            vv.y = (vv.y > 0.f) ? vv.y : expm1f(vv.y);
            vv.z = (vv.z > 0.f) ? vv.z : expm1f(vv.z);
            vv.w = (vv.w > 0.f) ? vv.w : expm1f(vv.w);
        }
        *(float4*)&C[(size_t)gr * 512 + col0 + tx * 4] = vv;
    }
}

// ---------------- launch ----------------
extern "C" void kernel_launch(void* const* d_in, const int* in_sizes, int n_in,
                              void* d_out, int out_size, void* d_ws, size_t ws_size,
                              hipStream_t stream) {
    const float* h   = (const float*)d_in[0];
    const int*   src = (const int*)d_in[1];
    const int*   dst = (const int*)d_in[2];
    const float* ew  = (const float*)d_in[3];
    const float* Wl[3] = {(const float*)d_in[4], (const float*)d_in[6], (const float*)d_in[8]};
    const float* bl[3] = {(const float*)d_in[5], (const float*)d_in[7], (const float*)d_in[9]};
    float* out = (float*)d_out;

    char* ws = (char*)d_ws;
    float* bufA = (float*)ws;  ws += (size_t)TOT * 4;        // dropout output
    float* bufB = (float*)ws;  ws += (size_t)TOT * 4;        // aggregation output
    int* degi_in  = (int*)ws;  ws += N_NODES * 4;
    int* degi_out = (int*)ws;  ws += N_NODES * 4;
    int* row_ptr  = (int*)ws;  ws += (N_NODES + 1) * 4;
    int* cursor   = (int*)ws;  ws += N_NODES * 4;
    int* csr_src  = (int*)ws;  ws += N_EDGES * 4;
    float* csr_w  = (float*)ws; ws += N_EDGES * 4;
    float* rn_in  = (float*)ws; ws += N_NODES * 4;
    float* rn_out = (float*)ws; ws += N_NODES * 4;

    hipMemsetAsync(degi_in, 0, N_NODES * 4, stream);
    hipMemsetAsync(degi_out, 0, N_NODES * 4, stream);
    hipMemsetAsync(cursor, 0, N_NODES * 4, stream);

    hist_kernel<<<(N_EDGES + 255) / 256, 256, 0, stream>>>(src, dst, degi_out, degi_in);
    scan_kernel<<<1, 256, 0, stream>>>(degi_in, degi_out, row_ptr, rn_in, rn_out);
    fill_kernel<<<(N_EDGES + 255) / 256, 256, 0, stream>>>(src, dst, ew, row_ptr, cursor,
                                                           csr_src, csr_w);

    // Partitionable split (JAX >= 0.4.30 default): subkey i = both lanes of
    // cipher(key=(0,42), x0=0, x1=i).
    uint32_t dk[3][2];
    for (int i = 0; i < 3; ++i) {
        uint32_t c0 = 0u, c1 = (uint32_t)i;
        tf2x32(0u, 42u, c0, c1);
        dk[i][0] = c0; dk[i][1] = c1;
    }

    for (int l = 0; l < 3; ++l) {
        const float* xin = (l == 0) ? h : out;
        dropout_kernel<<<(TOT / 4 + 255) / 256, 256, 0, stream>>>(xin, bufA, rn_out,
                                                                  dk[l][0], dk[l][1]);
        aggregate_kernel<<<N_NODES, 128, 0, stream>>>(bufA, row_ptr, csr_src, csr_w, bufB);
        gemm_kernel<<<dim3(512 / BN, (N_NODES + BM - 1) / BM), 256, 0, stream>>>(
            bufB, Wl[l], bl[l], rn_in, out, (l < 2) ? 1 : 0);
    }
}

// Round 3
// 327.327 us; speedup vs baseline: 1.9448x; 1.9448x over previous
//
#include <hip/hip_runtime.h>
#include <stdint.h>

#define N_NODES 10000
#define N_EDGES 160000
#define D 512
#define TOT (N_NODES * D)          // 5,120,000
#define M_PAD 10112                // 79 * 128, GEMM M coverage

typedef _Float16 h8 __attribute__((ext_vector_type(8)));
typedef float f4 __attribute__((ext_vector_type(4)));

// ---------------- threefry2x32 (JAX partitionable semantics) ----------------
__host__ __device__ inline uint32_t rotl32(uint32_t v, int r) {
    return (v << r) | (v >> (32 - r));
}

__host__ __device__ inline void tf2x32(uint32_t k0, uint32_t k1,
                                       uint32_t& x0, uint32_t& x1) {
    uint32_t k2 = k0 ^ k1 ^ 0x1BD11BDAu;
    x0 += k0; x1 += k1;
    x0 += x1; x1 = rotl32(x1, 13); x1 ^= x0;
    x0 += x1; x1 = rotl32(x1, 15); x1 ^= x0;
    x0 += x1; x1 = rotl32(x1, 26); x1 ^= x0;
    x0 += x1; x1 = rotl32(x1,  6); x1 ^= x0;
    x0 += k1; x1 += k2 + 1u;
    x0 += x1; x1 = rotl32(x1, 17); x1 ^= x0;
    x0 += x1; x1 = rotl32(x1, 29); x1 ^= x0;
    x0 += x1; x1 = rotl32(x1, 16); x1 ^= x0;
    x0 += x1; x1 = rotl32(x1, 24); x1 ^= x0;
    x0 += k2; x1 += k0 + 2u;
    x0 += x1; x1 = rotl32(x1, 13); x1 ^= x0;
    x0 += x1; x1 = rotl32(x1, 15); x1 ^= x0;
    x0 += x1; x1 = rotl32(x1, 26); x1 ^= x0;
    x0 += x1; x1 = rotl32(x1,  6); x1 ^= x0;
    x0 += k0; x1 += k1 + 3u;
    x0 += x1; x1 = rotl32(x1, 17); x1 ^= x0;
    x0 += x1; x1 = rotl32(x1, 29); x1 ^= x0;
    x0 += x1; x1 = rotl32(x1, 16); x1 ^= x0;
    x0 += x1; x1 = rotl32(x1, 24); x1 ^= x0;
    x0 += k1; x1 += k2 + 4u;
    x0 += x1; x1 = rotl32(x1, 13); x1 ^= x0;
    x0 += x1; x1 = rotl32(x1, 15); x1 ^= x0;
    x0 += x1; x1 = rotl32(x1, 26); x1 ^= x0;
    x0 += x1; x1 = rotl32(x1,  6); x1 ^= x0;
    x0 += k2; x1 += k0 + 5u;
}

__device__ __forceinline__ float dropout_gate(uint32_t k0, uint32_t k1, uint32_t j) {
    // returns 1.25 if kept else 0 (JAX: u<0.8 keep, scale 1/0.8)
    uint32_t c0 = 0u, c1 = j;
    tf2x32(k0, k1, c0, c1);
    uint32_t bits = c0 ^ c1;
    float u = __uint_as_float((bits >> 9) | 0x3f800000u) - 1.0f;
    return (u < 0.8f) ? 1.0f : 0.0f;
}

// async global->LDS, 16B per lane, dest = lds_base + lane*16
__device__ __forceinline__ void gl_lds16(const void* g, void* l) {
    __builtin_amdgcn_global_load_lds(
        (const __attribute__((address_space(1))) void*)g,
        (__attribute__((address_space(3))) void*)l, 16, 0, 0);
}

// ---------------- degree histogram ----------------
__global__ void hist_kernel(const int* __restrict__ src, const int* __restrict__ dst,
                            int* __restrict__ deg_out, int* __restrict__ deg_in) {
    int e = blockIdx.x * 256 + threadIdx.x;
    if (e >= N_EDGES) return;
    atomicAdd(&deg_out[src[e]], 1);
    atomicAdd(&deg_in[dst[e]], 1);
}

// ---------------- scan (wave-shuffle based) + norm factors ----------------
__global__ __launch_bounds__(1024)
void scan_kernel(const int* __restrict__ deg_in, const int* __restrict__ deg_out,
                 int* __restrict__ row_ptr,
                 float* __restrict__ rn_in, float* __restrict__ rn_out) {
    __shared__ int wsum[16];
    __shared__ int base_s;
    int tid = threadIdx.x;
    int lane = tid & 63, wv = tid >> 6;
    if (tid == 0) base_s = 0;
    __syncthreads();
    for (int start = 0; start < N_NODES; start += 1024) {
        int i = start + tid;
        int v = (i < N_NODES) ? deg_in[i] : 0;
        int s = v;
#pragma unroll
        for (int off = 1; off < 64; off <<= 1) {
            int t = __shfl_up(s, off, 64);
            if (lane >= off) s += t;
        }
        if (lane == 63) wsum[wv] = s;
        __syncthreads();
        if (wv == 0 && lane < 16) {
            int ws = wsum[lane];
#pragma unroll
            for (int off = 1; off < 16; off <<= 1) {
                int t = __shfl_up(ws, off, 64);
                if (lane >= off) ws += t;
            }
            wsum[lane] = ws;   // inclusive over wave sums
        }
        __syncthreads();
        if (i < N_NODES) {
            int prefix = base_s + ((wv > 0) ? wsum[wv - 1] : 0) + (s - v);
            row_ptr[i] = prefix;
            rn_in[i]  = 1.0f / sqrtf(fmaxf((float)v, 1.0f));
            rn_out[i] = 1.0f / sqrtf(fmaxf((float)deg_out[i], 1.0f));
        }
        __syncthreads();
        if (tid == 0) base_s += wsum[15];
        __syncthreads();
    }
    if (tid == 0) row_ptr[N_NODES] = base_s;
}

// ---------------- CSR fill (edges grouped by dst) ----------------
__global__ void fill_kernel(const int* __restrict__ src, const int* __restrict__ dst,
                            const float* __restrict__ ew, const int* __restrict__ row_ptr,
                            int* __restrict__ cursor,
                            int* __restrict__ csr_src, float* __restrict__ csr_w) {
    int e = blockIdx.x * 256 + threadIdx.x;
    if (e >= N_EDGES) return;
    int v = dst[e];
    int pos = atomicAdd(&cursor[v], 1);
    int idx = row_ptr[v] + pos;
    csr_src[idx] = src[e];
    csr_w[idx] = ew[e];
}

// ---------------- W fp32 [K][N] -> Wt fp16 [N][K] (LDS tile transpose) ------
__global__ __launch_bounds__(256)
void wconvert_kernel(const float* __restrict__ W0, const float* __restrict__ W1,
                     const float* __restrict__ W2, _Float16* __restrict__ Wt) {
    __shared__ float tile[64][65];
    const float* W = (blockIdx.z == 0) ? W0 : (blockIdx.z == 1) ? W1 : W2;
    _Float16* T = Wt + (size_t)blockIdx.z * 512 * 512;
    int r0 = blockIdx.y * 64, c0 = blockIdx.x * 64;
    int t = threadIdx.x;
    int c = t & 63, rq = t >> 6;
#pragma unroll
    for (int i = 0; i < 16; ++i) {
        int r = rq + i * 4;
        tile[r][c] = W[(size_t)(r0 + r) * 512 + c0 + c];
    }
    __syncthreads();
    int k = t & 63, nq = t >> 6;
#pragma unroll
    for (int i = 0; i < 16; ++i) {
        int n = nq + i * 4;
        T[(size_t)(c0 + n) * 512 + r0 + k] = (_Float16)tile[k][n];
    }
}

// ---------------- dropout0: h fp32 -> y fp16 (mask + /0.8 + src-norm) -------
__global__ __launch_bounds__(256)
void dropout_kernel(const float* __restrict__ x, _Float16* __restrict__ y,
                    const float* __restrict__ rn_out, uint32_t k0, uint32_t k1) {
    int t = blockIdx.x * 256 + threadIdx.x;   // one float4 per thread
    int j = t * 4;
    if (j >= TOT) return;
    float4 xv = *(const float4*)&x[j];
    float w = rn_out[j >> 9];
    _Float16 r[4];
    uint32_t jj = (uint32_t)j;
#pragma unroll
    for (int i = 0; i < 4; ++i) {
        float g = dropout_gate(k0, k1, jj + (uint32_t)i);
        float xi = (&xv.x)[i];
        r[i] = (_Float16)(g * (xi / 0.8f) * w);
    }
    *(ushort4*)&y[j] = *(ushort4*)r;
}

// ---------------- aggregate: agg[v,:] = sum_e w_e * y[src_e,:] (fp16 rows) --
__global__ __launch_bounds__(256)
void aggregate_kernel(const _Float16* __restrict__ y, const int* __restrict__ row_ptr,
                      const int* __restrict__ csr_src, const float* __restrict__ csr_w,
                      _Float16* __restrict__ agg) {
    int node = blockIdx.x * 4 + (threadIdx.x >> 6);
    int lane = threadIdx.x & 63;
    if (node >= N_NODES) return;
    int beg = row_ptr[node], end = row_ptr[node + 1];
    float acc[8] = {0, 0, 0, 0, 0, 0, 0, 0};
    int k = beg;
    for (; k + 1 < end; k += 2) {           // 2 rows in flight
        int s0 = csr_src[k], s1 = csr_src[k + 1];
        float w0 = csr_w[k], w1 = csr_w[k + 1];
        h8 a = *(const h8*)&y[(size_t)s0 * 512 + lane * 8];
        h8 b = *(const h8*)&y[(size_t)s1 * 512 + lane * 8];
#pragma unroll
        for (int i = 0; i < 8; ++i) acc[i] += w0 * (float)a[i] + w1 * (float)b[i];
    }
    if (k < end) {
        int s0 = csr_src[k];
        float w0 = csr_w[k];
        h8 a = *(const h8*)&y[(size_t)s0 * 512 + lane * 8];
#pragma unroll
        for (int i = 0; i < 8; ++i) acc[i] += w0 * (float)a[i];
    }
    _Float16 r[8];
#pragma unroll
    for (int i = 0; i < 8; ++i) r[i] = (_Float16)acc[i];
    *(h8*)&agg[(size_t)node * 512 + lane * 8] = *(h8*)r;
}

// ---------------- fp16 MFMA GEMM, tile 128x64, BK=32 ------------------------
// C[M,512] = A[M,512] @ Wt[512,512]^T  (Wt is [N][K])
// epilogue: *rn_in + bias, then mode 0: ELU + dropout -> fp16 y
//                               mode 1: plain -> fp32 out
__global__ __launch_bounds__(256)
void gemm_kernel(const _Float16* __restrict__ A, const _Float16* __restrict__ Wt,
                 const float* __restrict__ bias, const float* __restrict__ rn_in,
                 const float* __restrict__ rn_out,
                 _Float16* __restrict__ yout, float* __restrict__ fout,
                 int mode, uint32_t k0, uint32_t k1) {
    __shared__ _Float16 As[128 * 32];   // 8 KB, row-major [row][k]
    __shared__ _Float16 Bs[64 * 32];    // 4 KB, row-major [n][k]
    int tid = threadIdx.x;
    int wv = tid >> 6, lane = tid & 63;
    int row0 = blockIdx.y * 128, col0 = blockIdx.x * 64;
    int wr = wv >> 1, wc = wv & 1;      // 2x2 wave grid: 64 rows x 32 cols each

    f4 acc[4][2];
#pragma unroll
    for (int i = 0; i < 4; ++i)
#pragma unroll
        for (int j = 0; j < 2; ++j) acc[i][j] = (f4){0.f, 0.f, 0.f, 0.f};

    // staging source addresses (16 rows x 32k per inst; lane -> row=lane/4, kc=(lane%4)*8)
    int kc = (lane & 3) * 8;
    const _Float16* pa0 = A + (size_t)(row0 + 32 * wv + (lane >> 2)) * 512 + kc;
    const _Float16* pa1 = pa0 + 16 * 512;
    const _Float16* pb  = Wt + (size_t)(col0 + 16 * wv + (lane >> 2)) * 512 + kc;
    _Float16* la0 = &As[(32 * wv) * 32];
    _Float16* la1 = &As[(32 * wv + 16) * 32];
    _Float16* lb  = &Bs[(16 * wv) * 32];

    int kf = (lane >> 4) * 8;           // k-chunk for fragments
    const _Float16* fa = &As[(wr * 64 + (lane & 15)) * 32 + kf];
    const _Float16* fb = &Bs[(wc * 32 + (lane & 15)) * 32 + kf];

    for (int kk = 0; kk < 512; kk += 32) {
        gl_lds16(pa0 + kk, la0);
        gl_lds16(pa1 + kk, la1);
        gl_lds16(pb + kk, lb);
        __syncthreads();
        h8 af[4], bf[2];
#pragma unroll
        for (int mt = 0; mt < 4; ++mt) af[mt] = *(const h8*)(fa + mt * 16 * 32);
#pragma unroll
        for (int nt = 0; nt < 2; ++nt) bf[nt] = *(const h8*)(fb + nt * 16 * 32);
#pragma unroll
        for (int mt = 0; mt < 4; ++mt)
#pragma unroll
            for (int nt = 0; nt < 2; ++nt)
                acc[mt][nt] = __builtin_amdgcn_mfma_f32_16x16x32_f16(
                    af[mt], bf[nt], acc[mt][nt], 0, 0, 0);
        __syncthreads();
    }

    // epilogue. C/D layout: col = lane&15, row = (lane>>4)*4 + reg
    int mbase = row0 + wr * 64;
    int nbase = col0 + wc * 32;
#pragma unroll
    for (int mt = 0; mt < 4; ++mt) {
#pragma unroll
        for (int nt = 0; nt < 2; ++nt) {
            int gr0 = mbase + mt * 16 + (lane >> 4) * 4;
            int gc = nbase + nt * 16 + (lane & 15);
            float bcol = bias[gc];
#pragma unroll
            for (int i = 0; i < 4; ++i) {
                int gr = gr0 + i;
                if (gr >= N_NODES) continue;
                float v = acc[mt][nt][i] * rn_in[gr] + bcol;
                if (mode == 0) {
                    v = (v > 0.f) ? v : expm1f(v);
                    float g = dropout_gate(k0, k1, (uint32_t)(gr * 512 + gc));
                    v = g * (v / 0.8f) * rn_out[gr];
                    yout[(size_t)gr * 512 + gc] = (_Float16)v;
                } else {
                    fout[(size_t)gr * 512 + gc] = v;
                }
            }
        }
    }
}

// ---------------- launch ----------------
extern "C" void kernel_launch(void* const* d_in, const int* in_sizes, int n_in,
                              void* d_out, int out_size, void* d_ws, size_t ws_size,
                              hipStream_t stream) {
    const float* h   = (const float*)d_in[0];
    const int*   src = (const int*)d_in[1];
    const int*   dst = (const int*)d_in[2];
    const float* ew  = (const float*)d_in[3];
    const float* W0  = (const float*)d_in[4];
    const float* b0  = (const float*)d_in[5];
    const float* W1  = (const float*)d_in[6];
    const float* b1  = (const float*)d_in[7];
    const float* W2  = (const float*)d_in[8];
    const float* b2  = (const float*)d_in[9];
    const float* bl[3] = {b0, b1, b2};
    float* out = (float*)d_out;

    char* ws = (char*)d_ws;
    _Float16* y16  = (_Float16*)ws; ws += (size_t)TOT * 2;            // 10.24 MB
    _Float16* aggF = (_Float16*)ws; ws += (size_t)M_PAD * 512 * 2;    // 10.35 MB
    _Float16* Wt   = (_Float16*)ws; ws += (size_t)3 * 512 * 512 * 2;  // 1.57 MB
    int* degi_in  = (int*)ws;  ws += N_NODES * 4;
    int* degi_out = (int*)ws;  ws += N_NODES * 4;
    int* row_ptr  = (int*)ws;  ws += (N_NODES + 1) * 4;
    int* cursor   = (int*)ws;  ws += N_NODES * 4;
    int* csr_src  = (int*)ws;  ws += N_EDGES * 4;
    float* csr_w  = (float*)ws; ws += N_EDGES * 4;
    float* rn_in  = (float*)ws; ws += N_NODES * 4;
    float* rn_out = (float*)ws; ws += N_NODES * 4;

    hipMemsetAsync(degi_in, 0, N_NODES * 4, stream);
    hipMemsetAsync(degi_out, 0, N_NODES * 4, stream);
    hipMemsetAsync(cursor, 0, N_NODES * 4, stream);

    hist_kernel<<<(N_EDGES + 255) / 256, 256, 0, stream>>>(src, dst, degi_out, degi_in);
    scan_kernel<<<1, 1024, 0, stream>>>(degi_in, degi_out, row_ptr, rn_in, rn_out);
    fill_kernel<<<(N_EDGES + 255) / 256, 256, 0, stream>>>(src, dst, ew, row_ptr, cursor,
                                                           csr_src, csr_w);
    wconvert_kernel<<<dim3(8, 8, 3), 256, 0, stream>>>(W0, W1, W2, Wt);

    // partitionable split: subkey i = both lanes of cipher(key=(0,42), x0=0, x1=i)
    uint32_t dk[3][2];
    for (int i = 0; i < 3; ++i) {
        uint32_t c0 = 0u, c1 = (uint32_t)i;
        tf2x32(0u, 42u, c0, c1);
        dk[i][0] = c0; dk[i][1] = c1;
    }

    dropout_kernel<<<(TOT / 4 + 255) / 256, 256, 0, stream>>>(h, y16, rn_out,
                                                              dk[0][0], dk[0][1]);
    for (int l = 0; l < 3; ++l) {
        aggregate_kernel<<<N_NODES / 4, 256, 0, stream>>>(y16, row_ptr, csr_src,
                                                          csr_w, aggF);
        int mode = (l < 2) ? 0 : 1;
        uint32_t dk0 = (l < 2) ? dk[l + 1][0] : 0u;
        uint32_t dk1 = (l < 2) ? dk[l + 1][1] : 0u;
        gemm_kernel<<<dim3(512 / 64, M_PAD / 128), 256, 0, stream>>>(
            aggF, Wt + (size_t)l * 512 * 512, bl[l], rn_in, rn_out,
            y16, out, mode, dk0, dk1);
    }
}

// Round 4
// 310.458 us; speedup vs baseline: 2.0505x; 1.0543x over previous
//
#include <hip/hip_runtime.h>
#include <stdint.h>

#define N_NODES 10000
#define N_EDGES 160000
#define D 512
#define TOT (N_NODES * D)          // 5,120,000
#define M_PAD 10112                // 79 * 128, GEMM M coverage

typedef _Float16 h8 __attribute__((ext_vector_type(8)));
typedef float f4 __attribute__((ext_vector_type(4)));

// ---------------- threefry2x32 (JAX partitionable semantics) ----------------
__host__ __device__ inline uint32_t rotl32(uint32_t v, int r) {
    return (v << r) | (v >> (32 - r));
}

__host__ __device__ inline void tf2x32(uint32_t k0, uint32_t k1,
                                       uint32_t& x0, uint32_t& x1) {
    uint32_t k2 = k0 ^ k1 ^ 0x1BD11BDAu;
    x0 += k0; x1 += k1;
    x0 += x1; x1 = rotl32(x1, 13); x1 ^= x0;
    x0 += x1; x1 = rotl32(x1, 15); x1 ^= x0;
    x0 += x1; x1 = rotl32(x1, 26); x1 ^= x0;
    x0 += x1; x1 = rotl32(x1,  6); x1 ^= x0;
    x0 += k1; x1 += k2 + 1u;
    x0 += x1; x1 = rotl32(x1, 17); x1 ^= x0;
    x0 += x1; x1 = rotl32(x1, 29); x1 ^= x0;
    x0 += x1; x1 = rotl32(x1, 16); x1 ^= x0;
    x0 += x1; x1 = rotl32(x1, 24); x1 ^= x0;
    x0 += k2; x1 += k0 + 2u;
    x0 += x1; x1 = rotl32(x1, 13); x1 ^= x0;
    x0 += x1; x1 = rotl32(x1, 15); x1 ^= x0;
    x0 += x1; x1 = rotl32(x1, 26); x1 ^= x0;
    x0 += x1; x1 = rotl32(x1,  6); x1 ^= x0;
    x0 += k0; x1 += k1 + 3u;
    x0 += x1; x1 = rotl32(x1, 17); x1 ^= x0;
    x0 += x1; x1 = rotl32(x1, 29); x1 ^= x0;
    x0 += x1; x1 = rotl32(x1, 16); x1 ^= x0;
    x0 += x1; x1 = rotl32(x1, 24); x1 ^= x0;
    x0 += k1; x1 += k2 + 4u;
    x0 += x1; x1 = rotl32(x1, 13); x1 ^= x0;
    x0 += x1; x1 = rotl32(x1, 15); x1 ^= x0;
    x0 += x1; x1 = rotl32(x1, 26); x1 ^= x0;
    x0 += x1; x1 = rotl32(x1,  6); x1 ^= x0;
    x0 += k2; x1 += k0 + 5u;
}

__device__ __forceinline__ float dropout_gate(uint32_t k0, uint32_t k1, uint32_t j) {
    uint32_t c0 = 0u, c1 = j;
    tf2x32(k0, k1, c0, c1);
    uint32_t bits = c0 ^ c1;
    float u = __uint_as_float((bits >> 9) | 0x3f800000u) - 1.0f;
    return (u < 0.8f) ? 1.0f : 0.0f;
}

// async global->LDS, 16B per lane, dest = lds_base + lane*16
__device__ __forceinline__ void gl_lds16(const void* g, void* l) {
    __builtin_amdgcn_global_load_lds(
        (const __attribute__((address_space(1))) void*)g,
        (__attribute__((address_space(3))) void*)l, 16, 0, 0);
}

// ---------------- degree histogram ----------------
__global__ void hist_kernel(const int* __restrict__ src, const int* __restrict__ dst,
                            int* __restrict__ deg_out, int* __restrict__ deg_in) {
    int e = blockIdx.x * 256 + threadIdx.x;
    if (e >= N_EDGES) return;
    atomicAdd(&deg_out[src[e]], 1);
    atomicAdd(&deg_in[dst[e]], 1);
}

// ---------------- scan (wave-shuffle based) + norm factors ----------------
__global__ __launch_bounds__(1024)
void scan_kernel(const int* __restrict__ deg_in, const int* __restrict__ deg_out,
                 int* __restrict__ row_ptr,
                 float* __restrict__ rn_in, float* __restrict__ rn_out) {
    __shared__ int wsum[16];
    __shared__ int base_s;
    int tid = threadIdx.x;
    int lane = tid & 63, wv = tid >> 6;
    if (tid == 0) base_s = 0;
    __syncthreads();
    for (int start = 0; start < N_NODES; start += 1024) {
        int i = start + tid;
        int v = (i < N_NODES) ? deg_in[i] : 0;
        int s = v;
#pragma unroll
        for (int off = 1; off < 64; off <<= 1) {
            int t = __shfl_up(s, off, 64);
            if (lane >= off) s += t;
        }
        if (lane == 63) wsum[wv] = s;
        __syncthreads();
        if (wv == 0 && lane < 16) {
            int ws = wsum[lane];
#pragma unroll
            for (int off = 1; off < 16; off <<= 1) {
                int t = __shfl_up(ws, off, 64);
                if (lane >= off) ws += t;
            }
            wsum[lane] = ws;
        }
        __syncthreads();
        if (i < N_NODES) {
            int prefix = base_s + ((wv > 0) ? wsum[wv - 1] : 0) + (s - v);
            row_ptr[i] = prefix;
            rn_in[i]  = 1.0f / sqrtf(fmaxf((float)v, 1.0f));
            rn_out[i] = 1.0f / sqrtf(fmaxf((float)deg_out[i], 1.0f));
        }
        __syncthreads();
        if (tid == 0) base_s += wsum[15];
        __syncthreads();
    }
    if (tid == 0) row_ptr[N_NODES] = base_s;
}

// ---------------- CSR fill (edges grouped by dst, packed {src, w_bits}) -----
__global__ void fill_kernel(const int* __restrict__ src, const int* __restrict__ dst,
                            const float* __restrict__ ew, const int* __restrict__ row_ptr,
                            int* __restrict__ cursor, int2* __restrict__ csr) {
    int e = blockIdx.x * 256 + threadIdx.x;
    if (e >= N_EDGES) return;
    int v = dst[e];
    int pos = atomicAdd(&cursor[v], 1);
    int idx = row_ptr[v] + pos;
    csr[idx] = make_int2(src[e], __float_as_int(ew[e]));
}

// ---------------- W fp32 [K][N] -> Wt fp16 [N][K] (LDS tile transpose) ------
__global__ __launch_bounds__(256)
void wconvert_kernel(const float* __restrict__ W0, const float* __restrict__ W1,
                     const float* __restrict__ W2, _Float16* __restrict__ Wt) {
    __shared__ float tile[64][65];
    const float* W = (blockIdx.z == 0) ? W0 : (blockIdx.z == 1) ? W1 : W2;
    _Float16* T = Wt + (size_t)blockIdx.z * 512 * 512;
    int r0 = blockIdx.y * 64, c0 = blockIdx.x * 64;
    int t = threadIdx.x;
    int c = t & 63, rq = t >> 6;
#pragma unroll
    for (int i = 0; i < 16; ++i) {
        int r = rq + i * 4;
        tile[r][c] = W[(size_t)(r0 + r) * 512 + c0 + c];
    }
    __syncthreads();
    int k = t & 63, nq = t >> 6;
#pragma unroll
    for (int i = 0; i < 16; ++i) {
        int n = nq + i * 4;
        T[(size_t)(c0 + n) * 512 + r0 + k] = (_Float16)tile[k][n];
    }
}

// ---------------- dropout0: h fp32 -> y fp16 (mask + /0.8 + src-norm) -------
__global__ __launch_bounds__(256)
void dropout_kernel(const float* __restrict__ x, _Float16* __restrict__ y,
                    const float* __restrict__ rn_out, uint32_t k0, uint32_t k1) {
    int t = blockIdx.x * 256 + threadIdx.x;
    int j = t * 4;
    if (j >= TOT) return;
    float4 xv = *(const float4*)&x[j];
    float w = rn_out[j >> 9];
    _Float16 r[4];
    uint32_t jj = (uint32_t)j;
#pragma unroll
    for (int i = 0; i < 4; ++i) {
        float g = dropout_gate(k0, k1, jj + (uint32_t)i);
        float xi = (&xv.x)[i];
        r[i] = (_Float16)(g * (xi / 0.8f) * w);
    }
    *(ushort4*)&y[j] = *(ushort4*)r;
}

// ---------------- aggregate: agg[v,:] = sum_e w_e * y[src_e,:] --------------
// 1 wave per node, 4-edge unroll for outstanding-load depth.
__global__ __launch_bounds__(256)
void aggregate_kernel(const _Float16* __restrict__ y, const int* __restrict__ row_ptr,
                      const int2* __restrict__ csr, _Float16* __restrict__ agg) {
    int node = blockIdx.x * 4 + (threadIdx.x >> 6);
    int lane = threadIdx.x & 63;
    if (node >= N_NODES) return;
    int beg = row_ptr[node], end = row_ptr[node + 1];
    float acc[8] = {0, 0, 0, 0, 0, 0, 0, 0};
    int k = beg;
    for (; k + 3 < end; k += 4) {
        int2 e0 = csr[k], e1 = csr[k + 1], e2 = csr[k + 2], e3 = csr[k + 3];
        h8 a0 = *(const h8*)&y[(size_t)e0.x * 512 + lane * 8];
        h8 a1 = *(const h8*)&y[(size_t)e1.x * 512 + lane * 8];
        h8 a2 = *(const h8*)&y[(size_t)e2.x * 512 + lane * 8];
        h8 a3 = *(const h8*)&y[(size_t)e3.x * 512 + lane * 8];
        float w0 = __int_as_float(e0.y), w1 = __int_as_float(e1.y);
        float w2 = __int_as_float(e2.y), w3 = __int_as_float(e3.y);
#pragma unroll
        for (int i = 0; i < 8; ++i)
            acc[i] += w0 * (float)a0[i] + w1 * (float)a1[i]
                    + w2 * (float)a2[i] + w3 * (float)a3[i];
    }
    for (; k < end; ++k) {
        int2 e0 = csr[k];
        float w0 = __int_as_float(e0.y);
        h8 a = *(const h8*)&y[(size_t)e0.x * 512 + lane * 8];
#pragma unroll
        for (int i = 0; i < 8; ++i) acc[i] += w0 * (float)a[i];
    }
    _Float16 r[8];
#pragma unroll
    for (int i = 0; i < 8; ++i) r[i] = (_Float16)acc[i];
    *(h8*)&agg[(size_t)node * 512 + lane * 8] = *(h8*)r;
}

// ---------------- fp16 MFMA GEMM, tile 128x64, BK=64 ------------------------
// C[M,512] = A[M,512] @ Wt[512,512]^T  (Wt is [N][K])
// epilogue: *rn_in + bias, then mode 0: ELU + dropout -> fp16 y
//                               mode 1: plain -> fp32 out
#define GBK 64
__global__ __launch_bounds__(256)
void gemm_kernel(const _Float16* __restrict__ A, const _Float16* __restrict__ Wt,
                 const float* __restrict__ bias, const float* __restrict__ rn_in,
                 const float* __restrict__ rn_out,
                 _Float16* __restrict__ yout, float* __restrict__ fout,
                 int mode, uint32_t k0, uint32_t k1) {
    __shared__ _Float16 As[128 * GBK];   // 16 KB, row-major [row][k]
    __shared__ _Float16 Bs[64 * GBK];    // 8 KB, row-major [n][k]
    int tid = threadIdx.x;
    int wv = tid >> 6, lane = tid & 63;
    int row0 = blockIdx.y * 128, col0 = blockIdx.x * 64;
    int wr = wv >> 1, wc = wv & 1;       // 2x2 wave grid: 64 rows x 32 cols each

    f4 acc[4][2];
#pragma unroll
    for (int i = 0; i < 4; ++i)
#pragma unroll
        for (int j = 0; j < 2; ++j) acc[i][j] = (f4){0.f, 0.f, 0.f, 0.f};

    // staging: each inst = 8 rows x 64 k (1 KB). lane -> row=lane>>3, kc=(lane&7)*8
    int srow = lane >> 3;
    int skc = (lane & 7) * 8;
    const _Float16* pa = A + (size_t)(row0 + 32 * wv + srow) * 512 + skc;
    const _Float16* pb = Wt + (size_t)(col0 + 16 * wv + srow) * 512 + skc;
    _Float16* la = &As[(32 * wv) * GBK];
    _Float16* lb = &Bs[(16 * wv) * GBK];

    int kf = (lane >> 4) * 8;            // k-chunk within 32-wide MFMA step
    const _Float16* fa = &As[(wr * 64 + (lane & 15)) * GBK + kf];
    const _Float16* fb = &Bs[(wc * 32 + (lane & 15)) * GBK + kf];

    for (int kk = 0; kk < 512; kk += GBK) {
#pragma unroll
        for (int r = 0; r < 4; ++r)
            gl_lds16(pa + (size_t)r * 8 * 512 + kk, la + (8 * r) * GBK);
#pragma unroll
        for (int r = 0; r < 2; ++r)
            gl_lds16(pb + (size_t)r * 8 * 512 + kk, lb + (8 * r) * GBK);
        __syncthreads();
#pragma unroll
        for (int ks = 0; ks < 2; ++ks) {
            h8 af[4], bf[2];
#pragma unroll
            for (int mt = 0; mt < 4; ++mt)
                af[mt] = *(const h8*)(fa + mt * 16 * GBK + ks * 32);
#pragma unroll
            for (int nt = 0; nt < 2; ++nt)
                bf[nt] = *(const h8*)(fb + nt * 16 * GBK + ks * 32);
#pragma unroll
            for (int mt = 0; mt < 4; ++mt)
#pragma unroll
                for (int nt = 0; nt < 2; ++nt)
                    acc[mt][nt] = __builtin_amdgcn_mfma_f32_16x16x32_f16(
                        af[mt], bf[nt], acc[mt][nt], 0, 0, 0);
        }
        __syncthreads();
    }

    // epilogue. C/D layout: col = lane&15, row = (lane>>4)*4 + reg
    int mbase = row0 + wr * 64;
    int nbase = col0 + wc * 32;
#pragma unroll
    for (int mt = 0; mt < 4; ++mt) {
#pragma unroll
        for (int nt = 0; nt < 2; ++nt) {
            int gr0 = mbase + mt * 16 + (lane >> 4) * 4;
            int gc = nbase + nt * 16 + (lane & 15);
            float bcol = bias[gc];
#pragma unroll
            for (int i = 0; i < 4; ++i) {
                int gr = gr0 + i;
                if (gr >= N_NODES) continue;
                float v = acc[mt][nt][i] * rn_in[gr] + bcol;
                if (mode == 0) {
                    v = (v > 0.f) ? v : expm1f(v);
                    float g = dropout_gate(k0, k1, (uint32_t)(gr * 512 + gc));
                    v = g * (v / 0.8f) * rn_out[gr];
                    yout[(size_t)gr * 512 + gc] = (_Float16)v;
                } else {
                    fout[(size_t)gr * 512 + gc] = v;
                }
            }
        }
    }
}

// ---------------- launch ----------------
extern "C" void kernel_launch(void* const* d_in, const int* in_sizes, int n_in,
                              void* d_out, int out_size, void* d_ws, size_t ws_size,
                              hipStream_t stream) {
    const float* h   = (const float*)d_in[0];
    const int*   src = (const int*)d_in[1];
    const int*   dst = (const int*)d_in[2];
    const float* ew  = (const float*)d_in[3];
    const float* W0  = (const float*)d_in[4];
    const float* b0  = (const float*)d_in[5];
    const float* W1  = (const float*)d_in[6];
    const float* b1  = (const float*)d_in[7];
    const float* W2  = (const float*)d_in[8];
    const float* b2  = (const float*)d_in[9];
    const float* bl[3] = {b0, b1, b2};
    float* out = (float*)d_out;

    char* ws = (char*)d_ws;
    _Float16* y16  = (_Float16*)ws; ws += (size_t)TOT * 2;            // 10.24 MB
    _Float16* aggF = (_Float16*)ws; ws += (size_t)M_PAD * 512 * 2;    // 10.35 MB
    _Float16* Wt   = (_Float16*)ws; ws += (size_t)3 * 512 * 512 * 2;  // 1.57 MB
    // the next three must stay contiguous: zeroed with ONE memset
    int* degi_in  = (int*)ws;  ws += N_NODES * 4;
    int* degi_out = (int*)ws;  ws += N_NODES * 4;
    int* cursor   = (int*)ws;  ws += N_NODES * 4;
    int* row_ptr  = (int*)ws;  ws += (N_NODES + 1) * 4;
    ws = (char*)(((uintptr_t)ws + 15) & ~(uintptr_t)15);
    int2* csr     = (int2*)ws; ws += (size_t)N_EDGES * 8;
    float* rn_in  = (float*)ws; ws += N_NODES * 4;
    float* rn_out = (float*)ws; ws += N_NODES * 4;

    hipMemsetAsync(degi_in, 0, 3 * N_NODES * 4, stream);

    hist_kernel<<<(N_EDGES + 255) / 256, 256, 0, stream>>>(src, dst, degi_out, degi_in);
    scan_kernel<<<1, 1024, 0, stream>>>(degi_in, degi_out, row_ptr, rn_in, rn_out);
    fill_kernel<<<(N_EDGES + 255) / 256, 256, 0, stream>>>(src, dst, ew, row_ptr,
                                                           cursor, csr);
    wconvert_kernel<<<dim3(8, 8, 3), 256, 0, stream>>>(W0, W1, W2, Wt);

    // partitionable split: subkey i = both lanes of cipher(key=(0,42), x0=0, x1=i)
    uint32_t dk[3][2];
    for (int i = 0; i < 3; ++i) {
        uint32_t c0 = 0u, c1 = (uint32_t)i;
        tf2x32(0u, 42u, c0, c1);
        dk[i][0] = c0; dk[i][1] = c1;
    }

    dropout_kernel<<<(TOT / 4 + 255) / 256, 256, 0, stream>>>(h, y16, rn_out,
                                                              dk[0][0], dk[0][1]);
    for (int l = 0; l < 3; ++l) {
        aggregate_kernel<<<N_NODES / 4, 256, 0, stream>>>(y16, row_ptr, csr, aggF);
        int mode = (l < 2) ? 0 : 1;
        uint32_t dk0 = (l < 2) ? dk[l + 1][0] : 0u;
        uint32_t dk1 = (l < 2) ? dk[l + 1][1] : 0u;
        gemm_kernel<<<dim3(512 / 64, M_PAD / 128), 256, 0, stream>>>(
            aggF, Wt + (size_t)l * 512 * 512, bl[l], rn_in, rn_out,
            y16, out, mode, dk0, dk1);
    }
}

// Round 5
// 308.886 us; speedup vs baseline: 2.0609x; 1.0051x over previous
//
#include <hip/hip_runtime.h>
#include <stdint.h>

#define N_NODES 10000
#define N_EDGES 160000
#define D 512
#define TOT (N_NODES * D)          // 5,120,000
#define M_PAD 10112                // 79 * 128, GEMM M coverage

typedef _Float16 h8 __attribute__((ext_vector_type(8)));
typedef float f4 __attribute__((ext_vector_type(4)));

// ---------------- threefry2x32 (JAX partitionable semantics) ----------------
__host__ __device__ inline uint32_t rotl32(uint32_t v, int r) {
    return (v << r) | (v >> (32 - r));
}

__host__ __device__ inline void tf2x32(uint32_t k0, uint32_t k1,
                                       uint32_t& x0, uint32_t& x1) {
    uint32_t k2 = k0 ^ k1 ^ 0x1BD11BDAu;
    x0 += k0; x1 += k1;
    x0 += x1; x1 = rotl32(x1, 13); x1 ^= x0;
    x0 += x1; x1 = rotl32(x1, 15); x1 ^= x0;
    x0 += x1; x1 = rotl32(x1, 26); x1 ^= x0;
    x0 += x1; x1 = rotl32(x1,  6); x1 ^= x0;
    x0 += k1; x1 += k2 + 1u;
    x0 += x1; x1 = rotl32(x1, 17); x1 ^= x0;
    x0 += x1; x1 = rotl32(x1, 29); x1 ^= x0;
    x0 += x1; x1 = rotl32(x1, 16); x1 ^= x0;
    x0 += x1; x1 = rotl32(x1, 24); x1 ^= x0;
    x0 += k2; x1 += k0 + 2u;
    x0 += x1; x1 = rotl32(x1, 13); x1 ^= x0;
    x0 += x1; x1 = rotl32(x1, 15); x1 ^= x0;
    x0 += x1; x1 = rotl32(x1, 26); x1 ^= x0;
    x0 += x1; x1 = rotl32(x1,  6); x1 ^= x0;
    x0 += k0; x1 += k1 + 3u;
    x0 += x1; x1 = rotl32(x1, 17); x1 ^= x0;
    x0 += x1; x1 = rotl32(x1, 29); x1 ^= x0;
    x0 += x1; x1 = rotl32(x1, 16); x1 ^= x0;
    x0 += x1; x1 = rotl32(x1, 24); x1 ^= x0;
    x0 += k1; x1 += k2 + 4u;
    x0 += x1; x1 = rotl32(x1, 13); x1 ^= x0;
    x0 += x1; x1 = rotl32(x1, 15); x1 ^= x0;
    x0 += x1; x1 = rotl32(x1, 26); x1 ^= x0;
    x0 += x1; x1 = rotl32(x1,  6); x1 ^= x0;
    x0 += k2; x1 += k0 + 5u;
}

__device__ __forceinline__ float dropout_gate(uint32_t k0, uint32_t k1, uint32_t j) {
    uint32_t c0 = 0u, c1 = j;
    tf2x32(k0, k1, c0, c1);
    uint32_t bits = c0 ^ c1;
    float u = __uint_as_float((bits >> 9) | 0x3f800000u) - 1.0f;
    return (u < 0.8f) ? 1.0f : 0.0f;
}

// ---------------- degree histogram ----------------
__global__ void hist_kernel(const int* __restrict__ src, const int* __restrict__ dst,
                            int* __restrict__ deg_out, int* __restrict__ deg_in) {
    int e = blockIdx.x * 256 + threadIdx.x;
    if (e >= N_EDGES) return;
    atomicAdd(&deg_out[src[e]], 1);
    atomicAdd(&deg_in[dst[e]], 1);
}

// ---------------- scan (wave-shuffle based) + norm factors ----------------
__global__ __launch_bounds__(1024)
void scan_kernel(const int* __restrict__ deg_in, const int* __restrict__ deg_out,
                 int* __restrict__ row_ptr,
                 float* __restrict__ rn_in, float* __restrict__ rn_out) {
    __shared__ int wsum[16];
    __shared__ int base_s;
    int tid = threadIdx.x;
    int lane = tid & 63, wv = tid >> 6;
    if (tid == 0) base_s = 0;
    __syncthreads();
    for (int start = 0; start < N_NODES; start += 1024) {
        int i = start + tid;
        int v = (i < N_NODES) ? deg_in[i] : 0;
        int s = v;
#pragma unroll
        for (int off = 1; off < 64; off <<= 1) {
            int t = __shfl_up(s, off, 64);
            if (lane >= off) s += t;
        }
        if (lane == 63) wsum[wv] = s;
        __syncthreads();
        if (wv == 0 && lane < 16) {
            int ws = wsum[lane];
#pragma unroll
            for (int off = 1; off < 16; off <<= 1) {
                int t = __shfl_up(ws, off, 64);
                if (lane >= off) ws += t;
            }
            wsum[lane] = ws;
        }
        __syncthreads();
        if (i < N_NODES) {
            int prefix = base_s + ((wv > 0) ? wsum[wv - 1] : 0) + (s - v);
            row_ptr[i] = prefix;
            rn_in[i]  = 1.0f / sqrtf(fmaxf((float)v, 1.0f));
            rn_out[i] = 1.0f / sqrtf(fmaxf((float)deg_out[i], 1.0f));
        }
        __syncthreads();
        if (tid == 0) base_s += wsum[15];
        __syncthreads();
    }
    if (tid == 0) row_ptr[N_NODES] = base_s;
}

// ---------------- CSR fill (edges grouped by dst, packed {src, w_bits}) -----
__global__ void fill_kernel(const int* __restrict__ src, const int* __restrict__ dst,
                            const float* __restrict__ ew, const int* __restrict__ row_ptr,
                            int* __restrict__ cursor, int2* __restrict__ csr) {
    int e = blockIdx.x * 256 + threadIdx.x;
    if (e >= N_EDGES) return;
    int v = dst[e];
    int pos = atomicAdd(&cursor[v], 1);
    int idx = row_ptr[v] + pos;
    csr[idx] = make_int2(src[e], __float_as_int(ew[e]));
}

// ---------------- W fp32 [K][N] -> Wt fp16 [N][K] (LDS tile transpose) ------
__global__ __launch_bounds__(256)
void wconvert_kernel(const float* __restrict__ W0, const float* __restrict__ W1,
                     const float* __restrict__ W2, _Float16* __restrict__ Wt) {
    __shared__ float tile[64][65];
    const float* W = (blockIdx.z == 0) ? W0 : (blockIdx.z == 1) ? W1 : W2;
    _Float16* T = Wt + (size_t)blockIdx.z * 512 * 512;
    int r0 = blockIdx.y * 64, c0 = blockIdx.x * 64;
    int t = threadIdx.x;
    int c = t & 63, rq = t >> 6;
#pragma unroll
    for (int i = 0; i < 16; ++i) {
        int r = rq + i * 4;
        tile[r][c] = W[(size_t)(r0 + r) * 512 + c0 + c];
    }
    __syncthreads();
    int k = t & 63, nq = t >> 6;
#pragma unroll
    for (int i = 0; i < 16; ++i) {
        int n = nq + i * 4;
        T[(size_t)(c0 + n) * 512 + r0 + k] = (_Float16)tile[k][n];
    }
}

// ---------------- dropout0: h fp32 -> y fp16 (mask + /0.8 + src-norm) -------
__global__ __launch_bounds__(256)
void dropout_kernel(const float* __restrict__ x, _Float16* __restrict__ y,
                    const float* __restrict__ rn_out, uint32_t k0, uint32_t k1) {
    int t = blockIdx.x * 256 + threadIdx.x;
    int j = t * 4;
    if (j >= TOT) return;
    float4 xv = *(const float4*)&x[j];
    float w = rn_out[j >> 9];
    _Float16 r[4];
    uint32_t jj = (uint32_t)j;
#pragma unroll
    for (int i = 0; i < 4; ++i) {
        float g = dropout_gate(k0, k1, jj + (uint32_t)i);
        float xi = (&xv.x)[i];
        r[i] = (_Float16)(g * (xi / 0.8f) * w);
    }
    *(ushort4*)&y[j] = *(ushort4*)r;
}

// ---------------- aggregate: agg[v,:] = sum_e w_e * y[src_e,:] --------------
// 1 wave per node, 4-edge unroll for outstanding-load depth.
__global__ __launch_bounds__(256)
void aggregate_kernel(const _Float16* __restrict__ y, const int* __restrict__ row_ptr,
                      const int2* __restrict__ csr, _Float16* __restrict__ agg) {
    int node = blockIdx.x * 4 + (threadIdx.x >> 6);
    int lane = threadIdx.x & 63;
    if (node >= N_NODES) return;
    int beg = row_ptr[node], end = row_ptr[node + 1];
    float acc[8] = {0, 0, 0, 0, 0, 0, 0, 0};
    int k = beg;
    for (; k + 3 < end; k += 4) {
        int2 e0 = csr[k], e1 = csr[k + 1], e2 = csr[k + 2], e3 = csr[k + 3];
        h8 a0 = *(const h8*)&y[(size_t)e0.x * 512 + lane * 8];
        h8 a1 = *(const h8*)&y[(size_t)e1.x * 512 + lane * 8];
        h8 a2 = *(const h8*)&y[(size_t)e2.x * 512 + lane * 8];
        h8 a3 = *(const h8*)&y[(size_t)e3.x * 512 + lane * 8];
        float w0 = __int_as_float(e0.y), w1 = __int_as_float(e1.y);
        float w2 = __int_as_float(e2.y), w3 = __int_as_float(e3.y);
#pragma unroll
        for (int i = 0; i < 8; ++i)
            acc[i] += w0 * (float)a0[i] + w1 * (float)a1[i]
                    + w2 * (float)a2[i] + w3 * (float)a3[i];
    }
    for (; k < end; ++k) {
        int2 e0 = csr[k];
        float w0 = __int_as_float(e0.y);
        h8 a = *(const h8*)&y[(size_t)e0.x * 512 + lane * 8];
#pragma unroll
        for (int i = 0; i < 8; ++i) acc[i] += w0 * (float)a[i];
    }
    _Float16 r[8];
#pragma unroll
    for (int i = 0; i < 8; ++i) r[i] = (_Float16)acc[i];
    *(h8*)&agg[(size_t)node * 512 + lane * 8] = *(h8*)r;
}

// ---------------- fp16 MFMA GEMM, tile 128x64, BK=32, reg-staged pipeline ---
// C[M,512] = A[M,512] @ Wt[512,512]^T  (Wt is [N][K])
// LDS rows padded to 40 halves (80 B): start banks cycle all 32 over 8 rows
// -> 2-way-only aliasing on b128 reads/writes (free per m136).
// Register prefetch of tile k+1 issued right after barrier -> global latency
// overlaps ds_read+MFMA; vmcnt wait lands before next ds_write, not barrier.
#define GBK 32
#define LDA 40
__global__ __launch_bounds__(256)
void gemm_kernel(const _Float16* __restrict__ A, const _Float16* __restrict__ Wt,
                 const float* __restrict__ bias, const float* __restrict__ rn_in,
                 const float* __restrict__ rn_out,
                 _Float16* __restrict__ yout, float* __restrict__ fout,
                 int mode, uint32_t k0, uint32_t k1) {
    __shared__ _Float16 As[128 * LDA];   // 10 KB
    __shared__ _Float16 Bs[64 * LDA];    // 5 KB
    int tid = threadIdx.x;
    int wv = tid >> 6, lane = tid & 63;

    // XCD-aware tile swizzle: dispatch id f = bx + by*8; xcd ~ f&7 owns the
    // contiguous tile range [xcd*79, (xcd+1)*79) -> row-groups stay on one XCD.
    int f = blockIdx.x + blockIdx.y * 8;
    int T = (f & 7) * 79 + (f >> 3);
    int row0 = (T >> 3) * 128, col0 = (T & 7) * 64;

    int wr = wv >> 1, wc = wv & 1;       // 2x2 wave grid: 64 rows x 32 cols each

    f4 acc[4][2];
#pragma unroll
    for (int i = 0; i < 4; ++i)
#pragma unroll
        for (int j = 0; j < 2; ++j) acc[i][j] = (f4){0.f, 0.f, 0.f, 0.f};

    // staging: A-tile 128x32 halves = 512 16B-chunks, 2/thread; B-tile 256, 1/thread
    int srow = tid >> 2;                 // 0..63
    int sseg = (tid & 3) * 8;            // k offset in halves
    const _Float16* gA0 = A + (size_t)(row0 + srow) * 512 + sseg;
    const _Float16* gA1 = gA0 + (size_t)64 * 512;
    const _Float16* gB  = Wt + (size_t)(col0 + srow) * 512 + sseg;
    _Float16* wA0 = &As[srow * LDA + sseg];
    _Float16* wA1 = &As[(64 + srow) * LDA + sseg];
    _Float16* wB  = &Bs[srow * LDA + sseg];

    int kf = (lane >> 4) * 8;            // k-chunk per quad
    const _Float16* fa = &As[(wr * 64 + (lane & 15)) * LDA + kf];
    const _Float16* fb = &Bs[(wc * 32 + (lane & 15)) * LDA + kf];

    h8 ra0 = *(const h8*)gA0;
    h8 ra1 = *(const h8*)gA1;
    h8 rb  = *(const h8*)gB;

    for (int kk = 0; kk < 512; kk += GBK) {
        *(h8*)wA0 = ra0;
        *(h8*)wA1 = ra1;
        *(h8*)wB  = rb;
        __syncthreads();
        if (kk + GBK < 512) {            // prefetch next tile into registers
            ra0 = *(const h8*)(gA0 + kk + GBK);
            ra1 = *(const h8*)(gA1 + kk + GBK);
            rb  = *(const h8*)(gB  + kk + GBK);
        }
        h8 af[4], bf[2];
#pragma unroll
        for (int mt = 0; mt < 4; ++mt) af[mt] = *(const h8*)(fa + mt * 16 * LDA);
#pragma unroll
        for (int nt = 0; nt < 2; ++nt) bf[nt] = *(const h8*)(fb + nt * 16 * LDA);
#pragma unroll
        for (int mt = 0; mt < 4; ++mt)
#pragma unroll
            for (int nt = 0; nt < 2; ++nt)
                acc[mt][nt] = __builtin_amdgcn_mfma_f32_16x16x32_f16(
                    af[mt], bf[nt], acc[mt][nt], 0, 0, 0);
        __syncthreads();
    }

    // epilogue. C/D layout: col = lane&15, row = (lane>>4)*4 + reg
    int mbase = row0 + wr * 64;
    int nbase = col0 + wc * 32;
#pragma unroll
    for (int mt = 0; mt < 4; ++mt) {
#pragma unroll
        for (int nt = 0; nt < 2; ++nt) {
            int gr0 = mbase + mt * 16 + (lane >> 4) * 4;
            int gc = nbase + nt * 16 + (lane & 15);
            float bcol = bias[gc];
#pragma unroll
            for (int i = 0; i < 4; ++i) {
                int gr = gr0 + i;
                if (gr >= N_NODES) continue;
                float v = acc[mt][nt][i] * rn_in[gr] + bcol;
                if (mode == 0) {
                    v = (v > 0.f) ? v : expm1f(v);
                    float g = dropout_gate(k0, k1, (uint32_t)(gr * 512 + gc));
                    v = g * (v / 0.8f) * rn_out[gr];
                    yout[(size_t)gr * 512 + gc] = (_Float16)v;
                } else {
                    fout[(size_t)gr * 512 + gc] = v;
                }
            }
        }
    }
}

// ---------------- launch ----------------
extern "C" void kernel_launch(void* const* d_in, const int* in_sizes, int n_in,
                              void* d_out, int out_size, void* d_ws, size_t ws_size,
                              hipStream_t stream) {
    const float* h   = (const float*)d_in[0];
    const int*   src = (const int*)d_in[1];
    const int*   dst = (const int*)d_in[2];
    const float* ew  = (const float*)d_in[3];
    const float* W0  = (const float*)d_in[4];
    const float* b0  = (const float*)d_in[5];
    const float* W1  = (const float*)d_in[6];
    const float* b1  = (const float*)d_in[7];
    const float* W2  = (const float*)d_in[8];
    const float* b2  = (const float*)d_in[9];
    const float* bl[3] = {b0, b1, b2};
    float* out = (float*)d_out;

    char* ws = (char*)d_ws;
    _Float16* y16  = (_Float16*)ws; ws += (size_t)TOT * 2;            // 10.24 MB
    _Float16* aggF = (_Float16*)ws; ws += (size_t)M_PAD * 512 * 2;    // 10.35 MB
    _Float16* Wt   = (_Float16*)ws; ws += (size_t)3 * 512 * 512 * 2;  // 1.57 MB
    // the next three must stay contiguous: zeroed with ONE memset
    int* degi_in  = (int*)ws;  ws += N_NODES * 4;
    int* degi_out = (int*)ws;  ws += N_NODES * 4;
    int* cursor   = (int*)ws;  ws += N_NODES * 4;
    int* row_ptr  = (int*)ws;  ws += (N_NODES + 1) * 4;
    ws = (char*)(((uintptr_t)ws + 15) & ~(uintptr_t)15);
    int2* csr     = (int2*)ws; ws += (size_t)N_EDGES * 8;
    float* rn_in  = (float*)ws; ws += N_NODES * 4;
    float* rn_out = (float*)ws; ws += N_NODES * 4;

    hipMemsetAsync(degi_in, 0, 3 * N_NODES * 4, stream);

    hist_kernel<<<(N_EDGES + 255) / 256, 256, 0, stream>>>(src, dst, degi_out, degi_in);
    scan_kernel<<<1, 1024, 0, stream>>>(degi_in, degi_out, row_ptr, rn_in, rn_out);
    fill_kernel<<<(N_EDGES + 255) / 256, 256, 0, stream>>>(src, dst, ew, row_ptr,
                                                           cursor, csr);
    wconvert_kernel<<<dim3(8, 8, 3), 256, 0, stream>>>(W0, W1, W2, Wt);

    // partitionable split: subkey i = both lanes of cipher(key=(0,42), x0=0, x1=i)
    uint32_t dk[3][2];
    for (int i = 0; i < 3; ++i) {
        uint32_t c0 = 0u, c1 = (uint32_t)i;
        tf2x32(0u, 42u, c0, c1);
        dk[i][0] = c0; dk[i][1] = c1;
    }

    dropout_kernel<<<(TOT / 4 + 255) / 256, 256, 0, stream>>>(h, y16, rn_out,
                                                              dk[0][0], dk[0][1]);
    for (int l = 0; l < 3; ++l) {
        aggregate_kernel<<<N_NODES / 4, 256, 0, stream>>>(y16, row_ptr, csr, aggF);
        int mode = (l < 2) ? 0 : 1;
        uint32_t dk0 = (l < 2) ? dk[l + 1][0] : 0u;
        uint32_t dk1 = (l < 2) ? dk[l + 1][1] : 0u;
        gemm_kernel<<<dim3(8, M_PAD / 128), 256, 0, stream>>>(
            aggF, Wt + (size_t)l * 512 * 512, bl[l], rn_in, rn_out,
            y16, out, mode, dk0, dk1);
    }
}